// Round 4
// baseline (88.840 us; speedup 1.0000x reference)
//
#include <hip/hip_runtime.h>

typedef float fx4 __attribute__((ext_vector_type(4)));

// Fast 8-point DCT-II (unnormalized: o[u] = sum_x a[x]*cos((2x+1)u*pi/16)),
// even/odd factored. All coefficients literal.
__device__ __forceinline__ void dct8(const float a[8], float o[8]) {
    const float s0 = a[0] + a[7], s1 = a[1] + a[6], s2 = a[2] + a[5], s3 = a[3] + a[4];
    const float d0 = a[0] - a[7], d1 = a[1] - a[6], d2 = a[2] - a[5], d3 = a[3] - a[4];
    const float ss0 = s0 + s3, ss1 = s1 + s2;
    const float ds0 = s0 - s3, ds1 = s1 - s2;
    o[0] = ss0 + ss1;
    o[4] = 0.70710678f * (ss0 - ss1);
    o[2] = fmaf(0.92387953f, ds0,  0.38268343f * ds1);
    o[6] = fmaf(0.38268343f, ds0, -0.92387953f * ds1);
    o[1] = fmaf(0.98078528f, d0, fmaf( 0.83146961f, d1, fmaf( 0.55557023f, d2,  0.19509032f * d3)));
    o[3] = fmaf(0.83146961f, d0, fmaf(-0.19509032f, d1, fmaf(-0.98078528f, d2, -0.55557023f * d3)));
    o[5] = fmaf(0.55557023f, d0, fmaf(-0.98078528f, d1, fmaf( 0.19509032f, d2,  0.83146961f * d3)));
    o[7] = fmaf(0.19509032f, d0, fmaf(-0.55557023f, d1, fmaf( 0.83146961f, d2, -0.98078528f * d3)));
}

// In-register 8x8 transpose across an aligned 8-lane group.
// r[j] = M[lane][j] on entry; r[j] = M[j][lane] on exit.
// 3 butterfly stages (xor 1,2,4), 4 exchanges/stage = 12 cross-lane ops total.
__device__ __forceinline__ void transpose8(float r[8], int lane) {
#pragma unroll
    for (int s = 0; s < 3; ++s) {
        const int m = 1 << s;
        const bool bit = (lane & m) != 0;
#pragma unroll
        for (int j0 = 0; j0 < 8; ++j0) {
            if ((j0 & m) == 0) {
                const int j1 = j0 | m;
                float send = bit ? r[j0] : r[j1];
                float recv = __shfl_xor(send, m, 8);
                r[j0] = bit ? recv : r[j0];
                r[j1] = bit ? r[j1] : recv;
            }
        }
    }
}

// 8 lanes per 8x8 block; lane l owns row l end-to-end:
//   coalesced float4 x2 load -> row dct8 -> reg transpose -> col dct8
//   -> scale -> reg transpose -> coalesced float4 x2 store (regular, cached).
__global__ __launch_bounds__(256) void dct8x8_kernel(const float* __restrict__ in,
                                                     float* __restrict__ out) {
    const int tid = blockIdx.x * 256 + threadIdx.x;   // grid divides exactly
    const int l = threadIdx.x & 7;

    // ---- load row l of the block (32 B, fully coalesced) ----
    const fx4* p = reinterpret_cast<const fx4*>(in) + (size_t)tid * 2;
    fx4 v0 = p[0];
    fx4 v1 = p[1];
    float a[8] = { v0[0], v0[1], v0[2], v0[3], v1[0], v1[1], v1[2], v1[3] };

    // ---- row pass ----
    float r[8];
    dct8(a, r);
    r[0] -= 1024.0f;          // global -128 shift only affects the row DC (8*128)

    // ---- transpose: lane now holds column l of the intermediate ----
    transpose8(r, l);

    // ---- column pass -> output column l ----
    float o[8];
    dct8(r, o);

    // ---- scale[u][l] = (0.5*alpha_u)(0.5*alpha_l) ----
    const float sl = (l == 0) ? 0.35355339059f : 0.5f;
#pragma unroll
    for (int u = 0; u < 8; ++u) o[u] *= sl * ((u == 0) ? 0.35355339059f : 0.5f);

    // ---- transpose back: lane holds output row l ----
    transpose8(o, l);

    // ---- coalesced regular store (L2/L3 write-back aggregation) ----
    fx4 q0 = { o[0], o[1], o[2], o[3] };
    fx4 q1 = { o[4], o[5], o[6], o[7] };
    fx4* qp = reinterpret_cast<fx4*>(out) + (size_t)tid * 2;
    qp[0] = q0;
    qp[1] = q1;
}

extern "C" void kernel_launch(void* const* d_in, const int* in_sizes, int n_in,
                              void* d_out, int out_size, void* d_ws, size_t ws_size,
                              hipStream_t stream) {
    const float* in = (const float*)d_in[0];
    float* out = (float*)d_out;
    const int n = in_sizes[0];          // 64*3*4096*64 = 50,331,648 floats
    const int nthreads = n / 8;         // one lane per block-row
    const int grid = (nthreads + 255) / 256;
    hipLaunchKernelGGL(dct8x8_kernel, dim3(grid), dim3(256), 0, stream,
                       in, out);
}